// Round 16
// baseline (218.404 us; speedup 1.0000x reference)
//
#include <hip/hip_runtime.h>
#include <hip/hip_fp16.h>

// GCN: 3x (x = silu(Dinv A Dinv (x W) + b)) -> mean-pool -> relu(pooled@Wro+bro) -> log_softmax
// y = (x@W)*dinv[row] fp16; out[c] = dinv[c]*(sum_{r->c} y[r] + y[c]) + b; x' = silu(out) fp16.
// CSR built once via atomic-free two-level counting sort (bucket hist/scan/scatter + in-bucket sort).
// k_sort2 additionally emits perm[]: nodes degree-sorted WITHIN each 128-node bucket, so each
// k_agg wave serves 8 nodes of near-identical degree (kills exec-mask divergence waste).
// GEMM: MFMA 16x16x32 f16, operand-swapped, W fragments pre-permuted fp16 (k_wt), no LDS.
// Aggregation: 8 nodes per wave (8 lanes/node), per-group CSR loop, packed fp16 adds, no reduction.
// Pooling: wave-per-slice partial sums + tiny per-graph readout. sums zeroed in k_scant.

#define CH 256          // edge chunks
#define BSH 7           // log2(nodes per bucket)
#define BNODES 128

typedef _Float16 half8 __attribute__((ext_vector_type(8)));
typedef float float4v __attribute__((ext_vector_type(4)));

// W fragment pre-permute: Wt[l][ct][ks][kg][c16][j] = (half)W_l[(ks*32+kg*8+j)*64 + ct*16+c16]
__global__ void k_wt(const float* __restrict__ W0, const float* __restrict__ W1,
                     const float* __restrict__ W2, __half* __restrict__ Wt) {
    const float* Ws[3] = {W0, W1, W2};
    const float* W = Ws[blockIdx.x];
    __half* out = Wt + blockIdx.x * 4096;
    for (int idx = threadIdx.x; idx < 4096; idx += 256) {
        int k = idx >> 6, feat = idx & 63;
        int ks = k >> 5, kg = (k >> 3) & 3, j = k & 7;
        int ct = feat >> 4, c16 = feat & 15;
        out[((ct * 2 + ks) * 4 + kg) * 128 + c16 * 8 + j] = __float2half_rn(W[k * 64 + feat]);
    }
}

// Phase 1: per-chunk histogram over target buckets (LDS atomics only).
__global__ __launch_bounds__(256) void k_hist(const int* __restrict__ col, int E, int Ec, int NB,
                                              int* __restrict__ histG) {
    __shared__ int h[1024];
    int c = blockIdx.x, tid = threadIdx.x;
    for (int i = tid; i < NB; i += 256) h[i] = 0;
    __syncthreads();
    int lo = c * Ec, hi = min(E, lo + Ec);
    for (int e = lo + tid; e < hi; e += 256) atomicAdd(&h[col[e] >> BSH], 1);
    __syncthreads();
    for (int i = tid; i < NB; i += 256) histG[c * NB + i] = h[i];
}

// Phase 2a: per bucket, exclusive scan across CH=256 chunks (one wave per bucket, 4 chunks/lane)
__global__ void k_scanb(int* __restrict__ histG, int NB, int* __restrict__ btot) {
    int b = blockIdx.x;
    int l = threadIdx.x;  // 0..63
    int v[4], p[4];
#pragma unroll
    for (int k = 0; k < 4; ++k) { v[k] = histG[(k * 64 + l) * NB + b]; p[k] = v[k]; }
    for (int off = 1; off < 64; off <<= 1) {
#pragma unroll
        for (int k = 0; k < 4; ++k) {
            int t = __shfl_up(p[k], off);
            if (l >= off) p[k] += t;
        }
    }
    int acc = 0;
#pragma unroll
    for (int k = 0; k < 4; ++k) {
        int tot = __shfl(p[k], 63);
        histG[(k * 64 + l) * NB + b] = acc + p[k] - v[k];
        acc += tot;
    }
    if (l == 0) btot[b] = acc;
}

// Phase 2b: exclusive scan of bucket totals -> bucket start offsets. Also zeroes sums[].
__global__ void k_scant(const int* __restrict__ btot, int NB, int E, int* __restrict__ bstart,
                        float* __restrict__ sums, int GF) {
    __shared__ int s[1024];
    int tid = threadIdx.x;
    for (int i = tid; i < GF; i += 1024) sums[i] = 0.f;
    int v = (tid < NB) ? btot[tid] : 0;
    s[tid] = v;
    __syncthreads();
    for (int off = 1; off < 1024; off <<= 1) {
        int t = (tid >= off) ? s[tid - off] : 0;
        __syncthreads();
        s[tid] += t;
        __syncthreads();
    }
    if (tid < NB) bstart[tid] = s[tid] - v;
    if (tid == 0) bstart[NB] = E;
}

// Phase 3: scatter edges into bucket-grouped order. LDS cursors, no global atomics.
__global__ __launch_bounds__(1024) void k_scatter(const int* __restrict__ col, const int* __restrict__ row,
                                                  int E, int Ec, int NB,
                                                  const int* __restrict__ histG,
                                                  const int* __restrict__ bstart,
                                                  unsigned int* __restrict__ edges) {
    __shared__ int cur[1024];
    int c = blockIdx.x, tid = threadIdx.x;
    for (int i = tid; i < NB; i += 1024) cur[i] = bstart[i] + histG[c * NB + i];
    __syncthreads();
    int lo = c * Ec, hi = min(E, lo + Ec);
    for (int e = lo + tid; e < hi; e += 1024) {
        int cc = col[e];
        int b = cc >> BSH;
        int pos = atomicAdd(&cur[b], 1);   // LDS atomic
        edges[pos] = (unsigned int)row[e] | ((unsigned int)(cc & (BNODES - 1)) << 25);
    }
}

// Phase 4: within each bucket, counting-sort edges by local node -> per-node CSR + dinv,
// and emit perm[]: bucket nodes ranked by degree (256-bin LDS hist + wave scan + LDS cursors).
// srcs stored PRE-SCALED (*8) = float4-chunk index of the source row.
__global__ __launch_bounds__(512) void k_sort2(const unsigned int* __restrict__ edges,
                                               const int* __restrict__ bstart, int N, int E, int NB,
                                               int* __restrict__ srcs, int* __restrict__ starts,
                                               float* __restrict__ dinv, int* __restrict__ perm) {
    __shared__ int cnt[BNODES];
    __shared__ int cur[BNODES];
    __shared__ int dh[256];
    int b = blockIdx.x, tid = threadIdx.x;
    if (tid < BNODES) cnt[tid] = 0;
    if (tid < 256) dh[tid] = 0;
    __syncthreads();
    int lo = bstart[b], hi = bstart[b + 1];
    for (int e = lo + tid; e < hi; e += 512) atomicAdd(&cnt[edges[e] >> 25], 1);
    __syncthreads();
    int ng = b * BNODES + tid;
    if (tid < BNODES && ng < N) atomicAdd(&dh[min(cnt[tid], 255)], 1);  // degree histogram
    if (tid < 64) {   // wave 0: exclusive scan of cnt[128], 2 elems/lane
        int v0 = cnt[tid], v1 = cnt[64 + tid];
        int p0 = v0, p1 = v1;
        for (int off = 1; off < 64; off <<= 1) {
            int t0 = __shfl_up(p0, off);
            int t1 = __shfl_up(p1, off);
            if (tid >= off) { p0 += t0; p1 += t1; }
        }
        int A = __shfl(p0, 63);
        cur[tid] = lo + p0 - v0;
        cur[64 + tid] = lo + A + p1 - v1;
    }
    __syncthreads();
    if (tid < BNODES && ng < N) {
        starts[ng] = cur[tid];
        dinv[ng] = rsqrtf((float)cnt[tid] + 1.0f);
    }
    if (b == 0 && tid == 0) starts[N] = E;
    if (tid < 64) {   // wave 0: in-place exclusive scan of dh[256], 4 bins/lane
        int v[4], pp[4];
#pragma unroll
        for (int k = 0; k < 4; ++k) { v[k] = dh[k * 64 + tid]; pp[k] = v[k]; }
        for (int off = 1; off < 64; off <<= 1) {
#pragma unroll
            for (int k = 0; k < 4; ++k) {
                int t2 = __shfl_up(pp[k], off);
                if (tid >= off) pp[k] += t2;
            }
        }
        int acc = 0;
#pragma unroll
        for (int k = 0; k < 4; ++k) {
            int tot = __shfl(pp[k], 63);
            dh[k * 64 + tid] = acc + pp[k] - v[k];
            acc += tot;
        }
    }
    __syncthreads();   // starts read out + dh scan done before cursors move
    if (tid < BNODES && ng < N) {
        int r = atomicAdd(&dh[min(cnt[tid], 255)], 1);   // rank within bucket by degree
        perm[b * BNODES + r] = ng;
    }
    for (int e = lo + tid; e < hi; e += 512) {
        unsigned int p = edges[e];
        int pos = atomicAdd(&cur[p >> 25], 1);   // LDS atomic
        srcs[pos] = (int)((p & 0x1FFFFFFu) << 3);   // pre-scaled: row * 8
    }
}

// MFMA GEMM: yh[r] = fp16((x[r] @ W) * dinv[r]). Operand-swapped, Wt fragments from global.
template <int IN_HALF>
__global__ __launch_bounds__(256) void k_gemm(const void* __restrict__ xin,
                                              const __half* __restrict__ Wt,
                                              const float* __restrict__ dinv,
                                              __half* __restrict__ yh, int N) {
    int tid = threadIdx.x;
    int lane = tid & 63, wv = tid >> 6;
    int c16 = lane & 15, kg = lane >> 4;
    const _Float16* wt = (const _Float16*)Wt;
    half8 bf[4][2];
#pragma unroll
    for (int ct = 0; ct < 4; ++ct)
#pragma unroll
        for (int ks = 0; ks < 2; ++ks)
            bf[ct][ks] = *(const half8*)(wt + ((ct * 2 + ks) * 4 + kg) * 128 + c16 * 8);

    int tiles = (N + 15) >> 4;
    for (int t = blockIdx.x * 4 + wv; t < tiles; t += gridDim.x * 4) {
        int base = t << 4;
        int arow = base + c16;
        bool valid = arow < N;
        half8 af0, af1;
        if (valid) {
            if (IN_HALF) {
                const __half* xh = (const __half*)xin;
                af0 = *(const half8*)(xh + (size_t)arow * 64 + kg * 8);
                af1 = *(const half8*)(xh + (size_t)arow * 64 + 32 + kg * 8);
            } else {
                const float* xf = (const float*)xin;
                float4 u0 = *(const float4*)(xf + (size_t)arow * 64 + kg * 8);
                float4 u1 = *(const float4*)(xf + (size_t)arow * 64 + kg * 8 + 4);
                float4 u2 = *(const float4*)(xf + (size_t)arow * 64 + 32 + kg * 8);
                float4 u3 = *(const float4*)(xf + (size_t)arow * 64 + 32 + kg * 8 + 4);
                af0[0]=(_Float16)u0.x; af0[1]=(_Float16)u0.y; af0[2]=(_Float16)u0.z; af0[3]=(_Float16)u0.w;
                af0[4]=(_Float16)u1.x; af0[5]=(_Float16)u1.y; af0[6]=(_Float16)u1.z; af0[7]=(_Float16)u1.w;
                af1[0]=(_Float16)u2.x; af1[1]=(_Float16)u2.y; af1[2]=(_Float16)u2.z; af1[3]=(_Float16)u2.w;
                af1[4]=(_Float16)u3.x; af1[5]=(_Float16)u3.y; af1[6]=(_Float16)u3.z; af1[7]=(_Float16)u3.w;
            }
        } else {
#pragma unroll
            for (int j = 0; j < 8; ++j) { af0[j] = (_Float16)0.f; af1[j] = (_Float16)0.f; }
        }
        float d = valid ? dinv[arow] : 0.f;
#pragma unroll
        for (int ct = 0; ct < 4; ++ct) {
            float4v c = {0.f, 0.f, 0.f, 0.f};
            c = __builtin_amdgcn_mfma_f32_16x16x32_f16(bf[ct][0], af0, c, 0, 0, 0);
            c = __builtin_amdgcn_mfma_f32_16x16x32_f16(bf[ct][1], af1, c, 0, 0, 0);
            if (valid) {
                float2 st;
                __half2* hp = (__half2*)&st;
                hp[0] = __float22half2_rn(make_float2(c[0] * d, c[1] * d));
                hp[1] = __float22half2_rn(make_float2(c[2] * d, c[3] * d));
                *(float2*)(yh + (size_t)arow * 64 + ct * 16 + kg * 4) = st;
            }
        }
    }
}

// 8 nodes per wave via perm[] (degree-uniform within wave): group g owns node perm[wv*8+g];
// lane i owns 16B chunk i. Per-group CSR loop, packed fp16 adds, NO cross-lane reduction.
__global__ __launch_bounds__(256) void k_agg(const int* __restrict__ starts,
                                             const int* __restrict__ srcs,   // pre-scaled *8
                                             const int* __restrict__ perm,
                                             const __half* __restrict__ yh,
                                             const float* __restrict__ dinv,
                                             const float* __restrict__ b,
                                             __half* __restrict__ xh, int N) {
    int wv = (blockIdx.x * blockDim.x + threadIdx.x) >> 6;
    int lane = threadIdx.x & 63;
    int g = lane >> 3, i = lane & 7;
    int p = wv * 8 + g;
    bool valid = p < N;
    int node = 0;
    const float4* y4 = (const float4*)yh;   // row = 8 float4 chunks
    __half2 a0, a1, a2, a3;
    a0 = a1 = a2 = a3 = __half2half2(__ushort_as_half((unsigned short)0));
    int s = 0, t = 0;
    if (valid) {
        node = perm[p];
        s = starts[node]; t = starts[node + 1];
        float4 raw = y4[(size_t)node * 8 + i];   // self loop
        const __half2* h = (const __half2*)&raw;
        a0 = h[0]; a1 = h[1]; a2 = h[2]; a3 = h[3];
    }
    int e = s;
    for (; e + 7 < t; e += 8) {
        float4 r[8];
#pragma unroll
        for (int k = 0; k < 8; ++k) r[k] = y4[(size_t)srcs[e + k] + i];
#pragma unroll
        for (int k = 0; k < 8; ++k) {
            const __half2* h = (const __half2*)&r[k];
            a0 = __hadd2(a0, h[0]); a1 = __hadd2(a1, h[1]);
            a2 = __hadd2(a2, h[2]); a3 = __hadd2(a3, h[3]);
        }
    }
    for (; e + 3 < t; e += 4) {
        float4 r[4];
#pragma unroll
        for (int k = 0; k < 4; ++k) r[k] = y4[(size_t)srcs[e + k] + i];
#pragma unroll
        for (int k = 0; k < 4; ++k) {
            const __half2* h = (const __half2*)&r[k];
            a0 = __hadd2(a0, h[0]); a1 = __hadd2(a1, h[1]);
            a2 = __hadd2(a2, h[2]); a3 = __hadd2(a3, h[3]);
        }
    }
    for (; e < t; ++e) {
        float4 r0 = y4[(size_t)srcs[e] + i];
        const __half2* h0 = (const __half2*)&r0;
        a0 = __hadd2(a0, h0[0]); a1 = __hadd2(a1, h0[1]);
        a2 = __hadd2(a2, h0[2]); a3 = __hadd2(a3, h0[3]);
    }
    if (valid) {
        float d = dinv[node];
        float4 b0 = ((const float4*)b)[2 * i];
        float4 b1 = ((const float4*)b)[2 * i + 1];
        float bb[8] = {b0.x, b0.y, b0.z, b0.w, b1.x, b1.y, b1.z, b1.w};
        float2 f0 = __half22float2(a0), f1 = __half22float2(a1);
        float2 f2 = __half22float2(a2), f3 = __half22float2(a3);
        float sums[8] = {f0.x, f0.y, f1.x, f1.y, f2.x, f2.y, f3.x, f3.y};
        float o[8];
#pragma unroll
        for (int f = 0; f < 8; ++f) {
            float v = d * sums[f] + bb[f];
            o[f] = v / (1.f + __expf(-v));
        }
        float4 outv;
        __half2* oh = (__half2*)&outv;
#pragma unroll
        for (int q = 0; q < 4; ++q) oh[q] = __float22half2_rn(make_float2(o[2 * q], o[2 * q + 1]));
        ((float4*)xh)[(size_t)node * 8 + i] = outv;
    }
}

// Pool phase 1: wave-per-slice partial sums. Lane = feature; flush on graph change.
__global__ __launch_bounds__(256) void k_pool1(const __half* __restrict__ xh,
                                               const int* __restrict__ batch, int N, int chunk,
                                               float* __restrict__ sums) {
    int wvg = blockIdx.x * 4 + (threadIdx.x >> 6);
    int lane = threadIdx.x & 63;
    int lo = wvg * chunk;
    int hi = min(N, lo + chunk);
    if (lo >= hi) return;
    float acc = 0.f;
    int gcur = batch[lo];
    for (int n = lo; n < hi; ++n) {
        int gn = batch[n];
        if (gn != gcur) {
            atomicAdd(&sums[gcur * 64 + lane], acc);
            acc = 0.f;
            gcur = gn;
        }
        acc += __half2float(xh[(size_t)n * 64 + lane]);
    }
    atomicAdd(&sums[gcur * 64 + lane], acc);
}

// Pool phase 2: one 64-thread block per graph: mean, readout linear+relu, log_softmax
__global__ void k_readout(const float* __restrict__ sums, const int* __restrict__ batch, int N,
                          const float* __restrict__ Wro, const float* __restrict__ bro,
                          float* __restrict__ out, int C) {
    int g = blockIdx.x;
    int j = threadIdx.x;
    __shared__ float sp[64];
    __shared__ float sl[32];
    int lo = 0, hb = N;
    while (lo < hb) { int m = (lo + hb) >> 1; if (batch[m] < g) lo = m + 1; else hb = m; }
    int lo2 = lo, hi2 = N;
    while (lo2 < hi2) { int m = (lo2 + hi2) >> 1; if (batch[m] < g + 1) lo2 = m + 1; else hi2 = m; }
    float cnt = fmaxf((float)(hi2 - lo), 1.0f);
    sp[j] = sums[g * 64 + j] / cnt;
    __syncthreads();
    if (j < C) {
        float a = bro[j];
        for (int k = 0; k < 64; ++k) a += sp[k] * Wro[k * C + j];
        sl[j] = fmaxf(a, 0.f);
    }
    __syncthreads();
    if (j == 0) {
        float m = -1e30f;
        for (int c = 0; c < C; ++c) m = fmaxf(m, sl[c]);
        float sum = 0.f;
        for (int c = 0; c < C; ++c) sum += __expf(sl[c] - m);
        float lse = m + __logf(sum);
        for (int c = 0; c < C; ++c) out[g * C + c] = sl[c] - lse;
    }
}

static inline size_t align256(size_t v) { return (v + 255) & ~(size_t)255; }

extern "C" void kernel_launch(void* const* d_in, const int* in_sizes, int n_in,
                              void* d_out, int out_size, void* d_ws, size_t ws_size,
                              hipStream_t stream) {
    const float* x    = (const float*)d_in[0];
    const int*   ei   = (const int*)d_in[1];
    const int*   batch= (const int*)d_in[2];
    const float* W[3] = {(const float*)d_in[4], (const float*)d_in[6], (const float*)d_in[8]};
    const float* b[3] = {(const float*)d_in[5], (const float*)d_in[7], (const float*)d_in[9]};
    const float* Wro  = (const float*)d_in[10];
    const float* bro  = (const float*)d_in[11];

    int N = in_sizes[2];
    int E = in_sizes[1] / 2;
    int C = in_sizes[10] / 64;
    int G = out_size / C;

    const int* row = ei;          // sources
    const int* col = ei + E;      // targets

    int NB = (N + BNODES - 1) >> BSH;      // target buckets (<=1024)
    int Ec = (E + CH - 1) / CH;            // edges per chunk

    char* ws = (char*)d_ws;
    size_t off = 0;
    float* dinv    = (float*)(ws + off);        off = align256(off + (size_t)N * 4);
    int*   histG   = (int*)(ws + off);          off = align256(off + (size_t)CH * NB * 4);
    int*   btot    = (int*)(ws + off);          off = align256(off + (size_t)NB * 4);
    int*   bstart  = (int*)(ws + off);          off = align256(off + (size_t)(NB + 1) * 4);
    unsigned int* edges  = (unsigned int*)(ws + off); off = align256(off + (size_t)E * 4);
    int*   srcs    = (int*)(ws + off);          off = align256(off + (size_t)E * 4);
    int*   starts  = (int*)(ws + off);          off = align256(off + (size_t)(N + 1) * 4);
    int*   perm    = (int*)(ws + off);          off = align256(off + (size_t)N * 4);
    __half* yh     = (__half*)(ws + off);       off = align256(off + (size_t)N * 64 * 2);
    __half* xh     = (__half*)(ws + off);       off = align256(off + (size_t)N * 64 * 2);
    float* sums    = (float*)(ws + off);        off = align256(off + (size_t)G * 64 * 4);
    __half* Wt     = (__half*)(ws + off);       off = align256(off + (size_t)3 * 4096 * 2);

    k_wt<<<3, 256, 0, stream>>>(W[0], W[1], W[2], Wt);
    k_hist<<<CH, 256, 0, stream>>>(col, E, Ec, NB, histG);
    k_scanb<<<NB, 64, 0, stream>>>(histG, NB, btot);
    k_scant<<<1, 1024, 0, stream>>>(btot, NB, E, bstart, sums, G * 64);
    k_scatter<<<CH, 1024, 0, stream>>>(col, row, E, Ec, NB, histG, bstart, edges);
    k_sort2<<<NB, 512, 0, stream>>>(edges, bstart, N, E, NB, srcs, starts, dinv, perm);

    int aggB = (N + 31) / 32;   // 8 nodes/wave, 4 waves/block = 32 nodes/block
    int gemmB = 1568;           // ~1 16-row tile per wave

    k_gemm<0><<<gemmB, 256, 0, stream>>>(x, Wt, dinv, yh, N);
    k_agg<<<aggB, 256, 0, stream>>>(starts, srcs, perm, yh, dinv, b[0], xh, N);
    k_gemm<1><<<gemmB, 256, 0, stream>>>(xh, Wt + 4096, dinv, yh, N);
    k_agg<<<aggB, 256, 0, stream>>>(starts, srcs, perm, yh, dinv, b[1], xh, N);
    k_gemm<1><<<gemmB, 256, 0, stream>>>(xh, Wt + 8192, dinv, yh, N);
    k_agg<<<aggB, 256, 0, stream>>>(starts, srcs, perm, yh, dinv, b[2], xh, N);

    int nwaves = 4096;
    int chunk = (N + nwaves - 1) / nwaves;
    k_pool1<<<nwaves / 4, 256, 0, stream>>>(xh, batch, N, chunk, sums);
    k_readout<<<G, 64, 0, stream>>>(sums, batch, N, Wro, bro, (float*)d_out, C);
}

// Round 17
// 200.806 us; speedup vs baseline: 1.0876x; 1.0876x over previous
//
#include <hip/hip_runtime.h>
#include <hip/hip_fp16.h>

// GCN: 3x (x = silu(Dinv A Dinv (x W) + b)) -> mean-pool -> relu(pooled@Wro+bro) -> log_softmax
// y = (x@W)*dinv[row] fp16; out[c] = dinv[c]*(sum_{r->c} y[r] + y[c]) + b; x' = silu(out) fp16.
// CSR built once via atomic-free two-level counting sort (round-11 proven hist/scan/scatter/sort).
// GEMM: MFMA 16x16x32 f16, operand-swapped (lane owns one x-row; 4 consecutive features/reg ->
//       packed 8B stores), W fragments pre-permuted fp16 by k_wt (no LDS, no syncthreads in loop).
// Aggregation: 8 nodes per wave (8 lanes/node), per-group CSR loop, packed fp16 adds, no reduction.
//       Nodes NOT degree-permuted: consecutive-node contiguity (starts/self-loop/writes/srcs
//       streams) beats degree uniformity (round-16 regression, reverted).
// Pooling: wave-per-slice partial sums + tiny per-graph readout. sums zeroed in k_scant.

#define CH 256          // edge chunks
#define BSH 7           // log2(nodes per bucket)
#define BNODES 128

typedef _Float16 half8 __attribute__((ext_vector_type(8)));
typedef float float4v __attribute__((ext_vector_type(4)));

// W fragment pre-permute: Wt[l][ct][ks][kg][c16][j] = (half)W_l[(ks*32+kg*8+j)*64 + ct*16+c16]
__global__ void k_wt(const float* __restrict__ W0, const float* __restrict__ W1,
                     const float* __restrict__ W2, __half* __restrict__ Wt) {
    const float* Ws[3] = {W0, W1, W2};
    const float* W = Ws[blockIdx.x];
    __half* out = Wt + blockIdx.x * 4096;
    for (int idx = threadIdx.x; idx < 4096; idx += 256) {
        int k = idx >> 6, feat = idx & 63;
        int ks = k >> 5, kg = (k >> 3) & 3, j = k & 7;
        int ct = feat >> 4, c16 = feat & 15;
        out[((ct * 2 + ks) * 4 + kg) * 128 + c16 * 8 + j] = __float2half_rn(W[k * 64 + feat]);
    }
}

// Phase 1: per-chunk histogram over target buckets (LDS atomics only).
__global__ __launch_bounds__(256) void k_hist(const int* __restrict__ col, int E, int Ec, int NB,
                                              int* __restrict__ histG) {
    __shared__ int h[1024];
    int c = blockIdx.x, tid = threadIdx.x;
    for (int i = tid; i < NB; i += 256) h[i] = 0;
    __syncthreads();
    int lo = c * Ec, hi = min(E, lo + Ec);
    for (int e = lo + tid; e < hi; e += 256) atomicAdd(&h[col[e] >> BSH], 1);
    __syncthreads();
    for (int i = tid; i < NB; i += 256) histG[c * NB + i] = h[i];
}

// Phase 2a: per bucket, exclusive scan across CH=256 chunks (one wave per bucket, 4 chunks/lane)
__global__ void k_scanb(int* __restrict__ histG, int NB, int* __restrict__ btot) {
    int b = blockIdx.x;
    int l = threadIdx.x;  // 0..63
    int v[4], p[4];
#pragma unroll
    for (int k = 0; k < 4; ++k) { v[k] = histG[(k * 64 + l) * NB + b]; p[k] = v[k]; }
    for (int off = 1; off < 64; off <<= 1) {
#pragma unroll
        for (int k = 0; k < 4; ++k) {
            int t = __shfl_up(p[k], off);
            if (l >= off) p[k] += t;
        }
    }
    int acc = 0;
#pragma unroll
    for (int k = 0; k < 4; ++k) {
        int tot = __shfl(p[k], 63);
        histG[(k * 64 + l) * NB + b] = acc + p[k] - v[k];
        acc += tot;
    }
    if (l == 0) btot[b] = acc;
}

// Phase 2b: exclusive scan of bucket totals -> bucket start offsets. Also zeroes sums[].
__global__ void k_scant(const int* __restrict__ btot, int NB, int E, int* __restrict__ bstart,
                        float* __restrict__ sums, int GF) {
    __shared__ int s[1024];
    int tid = threadIdx.x;
    for (int i = tid; i < GF; i += 1024) sums[i] = 0.f;
    int v = (tid < NB) ? btot[tid] : 0;
    s[tid] = v;
    __syncthreads();
    for (int off = 1; off < 1024; off <<= 1) {
        int t = (tid >= off) ? s[tid - off] : 0;
        __syncthreads();
        s[tid] += t;
        __syncthreads();
    }
    if (tid < NB) bstart[tid] = s[tid] - v;
    if (tid == 0) bstart[NB] = E;
}

// Phase 3: scatter edges into bucket-grouped order. LDS cursors, no global atomics.
__global__ __launch_bounds__(1024) void k_scatter(const int* __restrict__ col, const int* __restrict__ row,
                                                  int E, int Ec, int NB,
                                                  const int* __restrict__ histG,
                                                  const int* __restrict__ bstart,
                                                  unsigned int* __restrict__ edges) {
    __shared__ int cur[1024];
    int c = blockIdx.x, tid = threadIdx.x;
    for (int i = tid; i < NB; i += 1024) cur[i] = bstart[i] + histG[c * NB + i];
    __syncthreads();
    int lo = c * Ec, hi = min(E, lo + Ec);
    for (int e = lo + tid; e < hi; e += 1024) {
        int cc = col[e];
        int b = cc >> BSH;
        int pos = atomicAdd(&cur[b], 1);   // LDS atomic
        edges[pos] = (unsigned int)row[e] | ((unsigned int)(cc & (BNODES - 1)) << 25);
    }
}

// Phase 4: within each bucket, counting-sort edges by local node -> per-node CSR + dinv.
// srcs stored PRE-SCALED (*8) = float4-chunk index of the source row.
__global__ __launch_bounds__(512) void k_sort2(const unsigned int* __restrict__ edges,
                                               const int* __restrict__ bstart, int N, int E, int NB,
                                               int* __restrict__ srcs, int* __restrict__ starts,
                                               float* __restrict__ dinv) {
    __shared__ int cnt[BNODES];
    __shared__ int cur[BNODES];
    int b = blockIdx.x, tid = threadIdx.x;
    if (tid < BNODES) cnt[tid] = 0;
    __syncthreads();
    int lo = bstart[b], hi = bstart[b + 1];
    for (int e = lo + tid; e < hi; e += 512) atomicAdd(&cnt[edges[e] >> 25], 1);
    __syncthreads();
    if (tid < 64) {   // wave 0: exclusive scan of cnt[128], 2 elems/lane
        int v0 = cnt[tid], v1 = cnt[64 + tid];
        int p0 = v0, p1 = v1;
        for (int off = 1; off < 64; off <<= 1) {
            int t0 = __shfl_up(p0, off);
            int t1 = __shfl_up(p1, off);
            if (tid >= off) { p0 += t0; p1 += t1; }
        }
        int A = __shfl(p0, 63);
        cur[tid] = lo + p0 - v0;
        cur[64 + tid] = lo + A + p1 - v1;
    }
    __syncthreads();
    int ng = b * BNODES + tid;
    if (tid < BNODES && ng < N) {
        starts[ng] = cur[tid];
        dinv[ng] = rsqrtf((float)cnt[tid] + 1.0f);
    }
    if (b == 0 && tid == 0) starts[N] = E;
    __syncthreads();   // starts must be read out before cursors move
    for (int e = lo + tid; e < hi; e += 512) {
        unsigned int p = edges[e];
        int pos = atomicAdd(&cur[p >> 25], 1);   // LDS atomic
        srcs[pos] = (int)((p & 0x1FFFFFFu) << 3);   // pre-scaled: row * 8
    }
}

// MFMA GEMM: yh[r] = fp16((x[r] @ W) * dinv[r]).
// Operand-swapped: D = mfma(Wfrag, xfrag) -> lane owns one x-row (lane&15); reg q gives 4
// consecutive output features (ct*16 + kg*4 + q) -> packed 8B stores. Wt fragments from global.
template <int IN_HALF>
__global__ __launch_bounds__(256) void k_gemm(const void* __restrict__ xin,
                                              const __half* __restrict__ Wt,
                                              const float* __restrict__ dinv,
                                              __half* __restrict__ yh, int N) {
    int tid = threadIdx.x;
    int lane = tid & 63, wv = tid >> 6;
    int c16 = lane & 15, kg = lane >> 4;
    const _Float16* wt = (const _Float16*)Wt;
    half8 bf[4][2];
#pragma unroll
    for (int ct = 0; ct < 4; ++ct)
#pragma unroll
        for (int ks = 0; ks < 2; ++ks)
            bf[ct][ks] = *(const half8*)(wt + ((ct * 2 + ks) * 4 + kg) * 128 + c16 * 8);

    int tiles = (N + 15) >> 4;
    for (int t = blockIdx.x * 4 + wv; t < tiles; t += gridDim.x * 4) {
        int base = t << 4;
        int arow = base + c16;
        bool valid = arow < N;
        half8 af0, af1;
        if (valid) {
            if (IN_HALF) {
                const __half* xh = (const __half*)xin;
                af0 = *(const half8*)(xh + (size_t)arow * 64 + kg * 8);
                af1 = *(const half8*)(xh + (size_t)arow * 64 + 32 + kg * 8);
            } else {
                const float* xf = (const float*)xin;
                float4 u0 = *(const float4*)(xf + (size_t)arow * 64 + kg * 8);
                float4 u1 = *(const float4*)(xf + (size_t)arow * 64 + kg * 8 + 4);
                float4 u2 = *(const float4*)(xf + (size_t)arow * 64 + 32 + kg * 8);
                float4 u3 = *(const float4*)(xf + (size_t)arow * 64 + 32 + kg * 8 + 4);
                af0[0]=(_Float16)u0.x; af0[1]=(_Float16)u0.y; af0[2]=(_Float16)u0.z; af0[3]=(_Float16)u0.w;
                af0[4]=(_Float16)u1.x; af0[5]=(_Float16)u1.y; af0[6]=(_Float16)u1.z; af0[7]=(_Float16)u1.w;
                af1[0]=(_Float16)u2.x; af1[1]=(_Float16)u2.y; af1[2]=(_Float16)u2.z; af1[3]=(_Float16)u2.w;
                af1[4]=(_Float16)u3.x; af1[5]=(_Float16)u3.y; af1[6]=(_Float16)u3.z; af1[7]=(_Float16)u3.w;
            }
        } else {
#pragma unroll
            for (int j = 0; j < 8; ++j) { af0[j] = (_Float16)0.f; af1[j] = (_Float16)0.f; }
        }
        float d = valid ? dinv[arow] : 0.f;
#pragma unroll
        for (int ct = 0; ct < 4; ++ct) {
            float4v c = {0.f, 0.f, 0.f, 0.f};
            c = __builtin_amdgcn_mfma_f32_16x16x32_f16(bf[ct][0], af0, c, 0, 0, 0);
            c = __builtin_amdgcn_mfma_f32_16x16x32_f16(bf[ct][1], af1, c, 0, 0, 0);
            if (valid) {
                float2 st;
                __half2* hp = (__half2*)&st;
                hp[0] = __float22half2_rn(make_float2(c[0] * d, c[1] * d));
                hp[1] = __float22half2_rn(make_float2(c[2] * d, c[3] * d));
                *(float2*)(yh + (size_t)arow * 64 + ct * 16 + kg * 4) = st;
            }
        }
    }
}

// 8 nodes per wave: group g (8 lanes) owns node wave*8+g entirely; lane i owns 16B chunk i.
// Per-group loop over own CSR segment (8-edge unroll), packed fp16 adds, NO cross-lane reduction.
__global__ __launch_bounds__(256) void k_agg(const int* __restrict__ starts,
                                             const int* __restrict__ srcs,   // pre-scaled *8
                                             const __half* __restrict__ yh,
                                             const float* __restrict__ dinv,
                                             const float* __restrict__ b,
                                             __half* __restrict__ xh, int N) {
    int wv = (blockIdx.x * blockDim.x + threadIdx.x) >> 6;
    int lane = threadIdx.x & 63;
    int g = lane >> 3, i = lane & 7;
    int node = wv * 8 + g;
    bool valid = node < N;
    const float4* y4 = (const float4*)yh;   // row = 8 float4 chunks
    __half2 a0, a1, a2, a3;
    a0 = a1 = a2 = a3 = __half2half2(__ushort_as_half((unsigned short)0));
    int s = 0, t = 0;
    if (valid) {
        s = starts[node]; t = starts[node + 1];
        float4 raw = y4[(size_t)node * 8 + i];   // self loop
        const __half2* h = (const __half2*)&raw;
        a0 = h[0]; a1 = h[1]; a2 = h[2]; a3 = h[3];
    }
    int e = s;
    for (; e + 7 < t; e += 8) {
        float4 r[8];
#pragma unroll
        for (int k = 0; k < 8; ++k) r[k] = y4[(size_t)srcs[e + k] + i];
#pragma unroll
        for (int k = 0; k < 8; ++k) {
            const __half2* h = (const __half2*)&r[k];
            a0 = __hadd2(a0, h[0]); a1 = __hadd2(a1, h[1]);
            a2 = __hadd2(a2, h[2]); a3 = __hadd2(a3, h[3]);
        }
    }
    for (; e + 3 < t; e += 4) {
        float4 r[4];
#pragma unroll
        for (int k = 0; k < 4; ++k) r[k] = y4[(size_t)srcs[e + k] + i];
#pragma unroll
        for (int k = 0; k < 4; ++k) {
            const __half2* h = (const __half2*)&r[k];
            a0 = __hadd2(a0, h[0]); a1 = __hadd2(a1, h[1]);
            a2 = __hadd2(a2, h[2]); a3 = __hadd2(a3, h[3]);
        }
    }
    for (; e < t; ++e) {
        float4 r0 = y4[(size_t)srcs[e] + i];
        const __half2* h0 = (const __half2*)&r0;
        a0 = __hadd2(a0, h0[0]); a1 = __hadd2(a1, h0[1]);
        a2 = __hadd2(a2, h0[2]); a3 = __hadd2(a3, h0[3]);
    }
    if (valid) {
        float d = dinv[node];
        float4 b0 = ((const float4*)b)[2 * i];
        float4 b1 = ((const float4*)b)[2 * i + 1];
        float bb[8] = {b0.x, b0.y, b0.z, b0.w, b1.x, b1.y, b1.z, b1.w};
        float2 f0 = __half22float2(a0), f1 = __half22float2(a1);
        float2 f2 = __half22float2(a2), f3 = __half22float2(a3);
        float sums[8] = {f0.x, f0.y, f1.x, f1.y, f2.x, f2.y, f3.x, f3.y};
        float o[8];
#pragma unroll
        for (int f = 0; f < 8; ++f) {
            float v = d * sums[f] + bb[f];
            o[f] = v / (1.f + __expf(-v));
        }
        float4 outv;
        __half2* oh = (__half2*)&outv;
#pragma unroll
        for (int p = 0; p < 4; ++p) oh[p] = __float22half2_rn(make_float2(o[2 * p], o[2 * p + 1]));
        ((float4*)xh)[(size_t)node * 8 + i] = outv;
    }
}

// Pool phase 1: wave-per-slice partial sums. Lane = feature; flush on graph change.
__global__ __launch_bounds__(256) void k_pool1(const __half* __restrict__ xh,
                                               const int* __restrict__ batch, int N, int chunk,
                                               float* __restrict__ sums) {
    int wvg = blockIdx.x * 4 + (threadIdx.x >> 6);
    int lane = threadIdx.x & 63;
    int lo = wvg * chunk;
    int hi = min(N, lo + chunk);
    if (lo >= hi) return;
    float acc = 0.f;
    int gcur = batch[lo];
    for (int n = lo; n < hi; ++n) {
        int gn = batch[n];
        if (gn != gcur) {
            atomicAdd(&sums[gcur * 64 + lane], acc);
            acc = 0.f;
            gcur = gn;
        }
        acc += __half2float(xh[(size_t)n * 64 + lane]);
    }
    atomicAdd(&sums[gcur * 64 + lane], acc);
}

// Pool phase 2: one 64-thread block per graph: mean, readout linear+relu, log_softmax
__global__ void k_readout(const float* __restrict__ sums, const int* __restrict__ batch, int N,
                          const float* __restrict__ Wro, const float* __restrict__ bro,
                          float* __restrict__ out, int C) {
    int g = blockIdx.x;
    int j = threadIdx.x;
    __shared__ float sp[64];
    __shared__ float sl[32];
    int lo = 0, hb = N;
    while (lo < hb) { int m = (lo + hb) >> 1; if (batch[m] < g) lo = m + 1; else hb = m; }
    int lo2 = lo, hi2 = N;
    while (lo2 < hi2) { int m = (lo2 + hi2) >> 1; if (batch[m] < g + 1) lo2 = m + 1; else hi2 = m; }
    float cnt = fmaxf((float)(hi2 - lo), 1.0f);
    sp[j] = sums[g * 64 + j] / cnt;
    __syncthreads();
    if (j < C) {
        float a = bro[j];
        for (int k = 0; k < 64; ++k) a += sp[k] * Wro[k * C + j];
        sl[j] = fmaxf(a, 0.f);
    }
    __syncthreads();
    if (j == 0) {
        float m = -1e30f;
        for (int c = 0; c < C; ++c) m = fmaxf(m, sl[c]);
        float sum = 0.f;
        for (int c = 0; c < C; ++c) sum += __expf(sl[c] - m);
        float lse = m + __logf(sum);
        for (int c = 0; c < C; ++c) out[g * C + c] = sl[c] - lse;
    }
}

static inline size_t align256(size_t v) { return (v + 255) & ~(size_t)255; }

extern "C" void kernel_launch(void* const* d_in, const int* in_sizes, int n_in,
                              void* d_out, int out_size, void* d_ws, size_t ws_size,
                              hipStream_t stream) {
    const float* x    = (const float*)d_in[0];
    const int*   ei   = (const int*)d_in[1];
    const int*   batch= (const int*)d_in[2];
    const float* W[3] = {(const float*)d_in[4], (const float*)d_in[6], (const float*)d_in[8]};
    const float* b[3] = {(const float*)d_in[5], (const float*)d_in[7], (const float*)d_in[9]};
    const float* Wro  = (const float*)d_in[10];
    const float* bro  = (const float*)d_in[11];

    int N = in_sizes[2];
    int E = in_sizes[1] / 2;
    int C = in_sizes[10] / 64;
    int G = out_size / C;

    const int* row = ei;          // sources
    const int* col = ei + E;      // targets

    int NB = (N + BNODES - 1) >> BSH;      // target buckets (<=1024)
    int Ec = (E + CH - 1) / CH;            // edges per chunk

    char* ws = (char*)d_ws;
    size_t off = 0;
    float* dinv    = (float*)(ws + off);        off = align256(off + (size_t)N * 4);
    int*   histG   = (int*)(ws + off);          off = align256(off + (size_t)CH * NB * 4);
    int*   btot    = (int*)(ws + off);          off = align256(off + (size_t)NB * 4);
    int*   bstart  = (int*)(ws + off);          off = align256(off + (size_t)(NB + 1) * 4);
    unsigned int* edges  = (unsigned int*)(ws + off); off = align256(off + (size_t)E * 4);
    int*   srcs    = (int*)(ws + off);          off = align256(off + (size_t)E * 4);
    int*   starts  = (int*)(ws + off);          off = align256(off + (size_t)(N + 1) * 4);
    __half* yh     = (__half*)(ws + off);       off = align256(off + (size_t)N * 64 * 2);
    __half* xh     = (__half*)(ws + off);       off = align256(off + (size_t)N * 64 * 2);
    float* sums    = (float*)(ws + off);        off = align256(off + (size_t)G * 64 * 4);
    __half* Wt     = (__half*)(ws + off);       off = align256(off + (size_t)3 * 4096 * 2);

    k_wt<<<3, 256, 0, stream>>>(W[0], W[1], W[2], Wt);
    k_hist<<<CH, 256, 0, stream>>>(col, E, Ec, NB, histG);
    k_scanb<<<NB, 64, 0, stream>>>(histG, NB, btot);
    k_scant<<<1, 1024, 0, stream>>>(btot, NB, E, bstart, sums, G * 64);
    k_scatter<<<CH, 1024, 0, stream>>>(col, row, E, Ec, NB, histG, bstart, edges);
    k_sort2<<<NB, 512, 0, stream>>>(edges, bstart, N, E, NB, srcs, starts, dinv);

    int aggB = (N + 31) / 32;   // 8 nodes/wave, 4 waves/block = 32 nodes/block
    int gemmB = 1568;           // ~1 16-row tile per wave

    k_gemm<0><<<gemmB, 256, 0, stream>>>(x, Wt, dinv, yh, N);
    k_agg<<<aggB, 256, 0, stream>>>(starts, srcs, yh, dinv, b[0], xh, N);
    k_gemm<1><<<gemmB, 256, 0, stream>>>(xh, Wt + 4096, dinv, yh, N);
    k_agg<<<aggB, 256, 0, stream>>>(starts, srcs, yh, dinv, b[1], xh, N);
    k_gemm<1><<<gemmB, 256, 0, stream>>>(xh, Wt + 8192, dinv, yh, N);
    k_agg<<<aggB, 256, 0, stream>>>(starts, srcs, yh, dinv, b[2], xh, N);

    int nwaves = 4096;
    int chunk = (N + nwaves - 1) / nwaves;
    k_pool1<<<nwaves / 4, 256, 0, stream>>>(xh, batch, N, chunk, sums);
    k_readout<<<G, 64, 0, stream>>>(sums, batch, N, Wro, bro, (float*)d_out, C);
}